// Round 2
// baseline (249.155 us; speedup 1.0000x reference)
//
#include <hip/hip_runtime.h>
#include <hip/hip_bf16.h>

typedef __bf16 bf16x8 __attribute__((ext_vector_type(8)));
typedef __bf16 bf16x4 __attribute__((ext_vector_type(4)));
typedef float floatx4 __attribute__((ext_vector_type(4)));

#define IC 8
#define RC 8
#define PC 8
#define G_ 4
#define IPG 128
#define OPG 128

#define WROW 136   // padded LDS row stride (bf16 elems) for one-time W staging

// Grid: 512 blocks = 8 channels (blockIdx&7 -> XCD-pinned W_i) x 64.
// Block = 4 waves; each wave owns 128 rows (half a (b,i) slab) = 8 tiles of 16.
// W_i held entirely in VGPRs (32 bf16x8 frags, staged once via LDS).
// Main loop is barrier-free: 2-deep register prefetch (pfA/pfB), per-pair
// reload interleaved with MFMA, bias folded into acc init, nt dwordx4 stores.
__global__ __launch_bounds__(256, 2)
void mcsl_kernel(const float* __restrict__ x,
                 const float* __restrict__ W,
                 const float* __restrict__ bias,
                 float* __restrict__ y)
{
    __shared__ __align__(16) __bf16 Wlds[128 * WROW];
    __shared__ __align__(16) float blds[128];

    const int tid = threadIdx.x;
    const int i = blockIdx.x & 7;    // channel -> XCD pin
    const int j = blockIdx.x >> 3;   // 0..63: which pair of batch slabs

    // ---- stage W_i (128x128 fp32 -> bf16 LDS, padded rows) : once per block ----
    const float4* Wsrc = (const float4*)(W + (size_t)i * (OPG * IPG));
    #pragma unroll
    for (int it = 0; it < 16; ++it) {
        int idx = tid + it * 256;      // 4096 float4 total
        float4 w4 = Wsrc[idx];
        int o  = idx >> 5;             // 32 float4 per row
        int k4 = (idx & 31) << 2;
        bf16x4 wq;
        wq[0] = (__bf16)w4.x; wq[1] = (__bf16)w4.y;
        wq[2] = (__bf16)w4.z; wq[3] = (__bf16)w4.w;
        *(bf16x4*)&Wlds[o * WROW + k4] = wq;
    }
    if (tid < 128) blds[tid] = bias[i * OPG + tid];
    __syncthreads();

    const int lane = tid & 63;
    const int wv   = tid >> 6;      // wave 0..3
    const int nrow = lane & 15;
    const int quad = lane >> 4;

    // ---- hoist all of W_i into registers (A-operand layout) ----
    // lane holds W[out = ct*16 + nrow][k = ks*32 + quad*8 .. +7]
    bf16x8 wfrag[8][4];
    #pragma unroll
    for (int ct = 0; ct < 8; ++ct)
        #pragma unroll
        for (int ks = 0; ks < 4; ++ks)
            wfrag[ct][ks] = *(const bf16x8*)&Wlds[(ct * 16 + nrow) * WROW + ks * 32 + quad * 8];

    // ---- this wave's slab: b = 2j + (wv>>1); rows rhalf..rhalf+127 ----
    const int b = 2 * j + (wv >> 1);
    const size_t slab = ((size_t)(b * (IC * RC) + i * RC)) * (PC * G_ * IPG);
    const int rhalf = (wv & 1) * 128;

    const float4* xs = (const float4*)(x + slab);
    float*        ys = y + slab;   // same geometry (IPG == OPG)

    // per-lane tile source: row rhalf + T*16 + nrow (32 float4/row), cols quad*2 +
    // {ks*8, ks*8+1}  ->  k = ks*32 + quad*8 .. +7
#define TILE_SRC(T) (xs + (size_t)(rhalf + (T) * 16 + nrow) * 32 + quad * 2)

    float4 pfA[8], pfB[8];
    {
        const float4* s0 = TILE_SRC(0);
        const float4* s1 = TILE_SRC(1);
        #pragma unroll
        for (int ks = 0; ks < 4; ++ks) {
            pfA[2 * ks]     = s0[ks * 8];
            pfA[2 * ks + 1] = s0[ks * 8 + 1];
        }
        #pragma unroll
        for (int ks = 0; ks < 4; ++ks) {
            pfB[2 * ks]     = s1[ks * 8];
            pfB[2 * ks + 1] = s1[ks * 8 + 1];
        }
    }

    // One tile step: convert pair ks of BUF -> mfma; immediately re-issue that
    // pair for tile T+2 (PREF=1). acc init = bias broadcast from LDS.
#define TILE_STEP(T, BUF, PREF) do {                                            \
        floatx4 acc[8];                                                         \
        _Pragma("unroll")                                                       \
        for (int ct = 0; ct < 8; ++ct)                                          \
            acc[ct] = *(const floatx4*)&blds[ct * 16 + quad * 4];               \
        const float4* nsrc = (PREF) ? TILE_SRC((T) + 2) : xs;                   \
        _Pragma("unroll")                                                       \
        for (int ks = 0; ks < 4; ++ks) {                                        \
            float4 a0 = BUF[2 * ks], a1 = BUF[2 * ks + 1];                      \
            if (PREF) {                                                         \
                BUF[2 * ks]     = nsrc[ks * 8];                                 \
                BUF[2 * ks + 1] = nsrc[ks * 8 + 1];                             \
            }                                                                   \
            bf16x8 v;                                                           \
            v[0] = (__bf16)a0.x; v[1] = (__bf16)a0.y;                           \
            v[2] = (__bf16)a0.z; v[3] = (__bf16)a0.w;                           \
            v[4] = (__bf16)a1.x; v[5] = (__bf16)a1.y;                           \
            v[6] = (__bf16)a1.z; v[7] = (__bf16)a1.w;                           \
            _Pragma("unroll")                                                   \
            for (int ct = 0; ct < 8; ++ct)                                      \
                acc[ct] = __builtin_amdgcn_mfma_f32_16x16x32_bf16(              \
                              wfrag[ct][ks], v, acc[ct], 0, 0, 0);              \
        }                                                                       \
        float* yrow = ys + (size_t)(rhalf + (T) * 16 + nrow) * OPG + quad * 4;  \
        _Pragma("unroll")                                                       \
        for (int ct = 0; ct < 8; ++ct)                                          \
            __builtin_nontemporal_store(acc[ct], (floatx4*)(yrow + ct * 16));   \
    } while (0)

    TILE_STEP(0, pfA, 1);
    TILE_STEP(1, pfB, 1);
    TILE_STEP(2, pfA, 1);
    TILE_STEP(3, pfB, 1);
    TILE_STEP(4, pfA, 1);
    TILE_STEP(5, pfB, 1);
    TILE_STEP(6, pfA, 0);
    TILE_STEP(7, pfB, 0);

#undef TILE_STEP
#undef TILE_SRC
}

extern "C" void kernel_launch(void* const* d_in, const int* in_sizes, int n_in,
                              void* d_out, int out_size, void* d_ws, size_t ws_size,
                              hipStream_t stream) {
    const float* x = (const float*)d_in[0];
    const float* W = (const float*)d_in[1];
    const float* b = (const float*)d_in[2];
    float* y = (float*)d_out;
    dim3 grid(512), block(256);
    hipLaunchKernelGGL(mcsl_kernel, grid, block, 0, stream, x, W, b, y);
}